// Round 12
// baseline (172.447 us; speedup 1.0000x reference)
//
#include <hip/hip_runtime.h>

// B=256, T=5, S=64, F=256, H=4, Fh=64, N=H*B=1024, M=81920 rows of [.,256]

typedef unsigned short ushort_t;
typedef __attribute__((ext_vector_type(8))) short bf16x8;
typedef __attribute__((ext_vector_type(4))) float f32x4;

__device__ inline ushort_t f2bf(float f) {            // RNE f32 -> bf16
  unsigned u = __float_as_uint(f);
  return (ushort_t)((u + 0x7FFFu + ((u >> 16) & 1u)) >> 16);
}
__device__ inline float bflo(unsigned u) { return __uint_as_float(u << 16); }
__device__ inline float bfhi(unsigned u) { return __uint_as_float(u & 0xFFFF0000u); }
__device__ inline uint4 pack8(float4 a, float4 b) {   // 8 f32 -> 8 bf16 in uint4
  uint4 r;
  r.x = (unsigned)f2bf(a.x) | ((unsigned)f2bf(a.y) << 16);
  r.y = (unsigned)f2bf(a.z) | ((unsigned)f2bf(a.w) << 16);
  r.z = (unsigned)f2bf(b.x) | ((unsigned)f2bf(b.y) << 16);
  r.w = (unsigned)f2bf(b.z) | ((unsigned)f2bf(b.w) << 16);
  return r;
}

// ---------------- fused prep: convert_w | prior | bias_prior_sum | k/xb -----------
// blocks [0,768): Wt[mat][n][k] = bf16(W[k][n])
// blocks [768,848): prior[t,s,c]
// blocks [848,2128): bps[nb,t,c] = sum_s bias*prior (prior recomputed inline)
// blocks [2128,4176): k[b,s,f] = sum_t u[t]*x -> bf16, and xb = bf16(x); 8 f/thread
__global__ __launch_bounds__(256) void prep_kernel(
    const float* __restrict__ x, const float* __restrict__ u,
    const float* __restrict__ Wq, const float* __restrict__ Wv,
    const float* __restrict__ Wo, const float* __restrict__ dis,
    const float* __restrict__ sigma, const float* __restrict__ bias,
    ushort_t* __restrict__ Wt, float* __restrict__ prior,
    float* __restrict__ bps, ushort_t* __restrict__ kout,
    ushort_t* __restrict__ xb) {
  __shared__ float red[4][64];
  const int blk = blockIdx.x, tid = threadIdx.x;
  if (blk < 768) {
    int id = blk * 256 + tid;                  // 196608
    int mat = id >> 16, rem = id & 65535;
    int n = rem >> 8, k = rem & 255;
    const float* W = mat == 0 ? Wq : (mat == 1 ? Wv : Wo);
    Wt[id] = f2bf(W[k * 256 + n]);
  } else if (blk < 848) {
    int i = (blk - 768) * 256 + tid;           // 20480
    int ts = i >> 6;
    float sg = sigma[ts];
    float d = dis[i];
    prior[i] = 0.3989422804014327f / sg * __expf(-d * d / (2.f * sg * sg));
  } else if (blk < 2128) {
    int b2 = blk - 848;                        // nb*5 + t, 1280 blocks
    int t = b2 % 5;
    const float* bp = bias + (size_t)b2 * 4096;
    int c = tid & 63, sg_ = tid >> 6;
    float sum = 0.f;
    for (int s = sg_ * 16; s < sg_ * 16 + 16; ++s) {
      float sgm = sigma[t * 64 + s];
      float d = dis[t * 4096 + s * 64 + c];
      float pr = 0.3989422804014327f / sgm * __expf(-d * d / (2.f * sgm * sgm));
      sum += bp[s * 64 + c] * pr;
    }
    red[sg_][c] = sum;
    __syncthreads();
    if (tid < 64)
      bps[(size_t)b2 * 64 + tid] = red[0][tid] + red[1][tid] + red[2][tid] + red[3][tid];
  } else {
    int i = (blk - 2128) * 256 + tid;          // 8-float id, 524288 total
    size_t j = (size_t)i * 8;
    int b = (int)(j >> 14);
    int off = (int)(j & 16383);
    const float* xp = x + (size_t)b * 81920 + off;
    ushort_t* xq = xb + (size_t)b * 81920 + off;
    float u0 = u[0], u1 = u[1], u2 = u[2], u3 = u[3], u4 = u[4];
    float4 lo[5], hi[5];
#pragma unroll
    for (int t = 0; t < 5; ++t) {
      lo[t] = *(const float4*)(xp + t * 16384);
      hi[t] = *(const float4*)(xp + t * 16384 + 4);
    }
#pragma unroll
    for (int t = 0; t < 5; ++t)
      *(uint4*)(xq + t * 16384) = pack8(lo[t], hi[t]);
    float4 rl, rh;
    rl.x = u0*lo[0].x + u1*lo[1].x + u2*lo[2].x + u3*lo[3].x + u4*lo[4].x;
    rl.y = u0*lo[0].y + u1*lo[1].y + u2*lo[2].y + u3*lo[3].y + u4*lo[4].y;
    rl.z = u0*lo[0].z + u1*lo[1].z + u2*lo[2].z + u3*lo[3].z + u4*lo[4].z;
    rl.w = u0*lo[0].w + u1*lo[1].w + u2*lo[2].w + u3*lo[3].w + u4*lo[4].w;
    rh.x = u0*hi[0].x + u1*hi[1].x + u2*hi[2].x + u3*hi[3].x + u4*hi[4].x;
    rh.y = u0*hi[0].y + u1*hi[1].y + u2*hi[2].y + u3*hi[3].y + u4*hi[4].y;
    rh.z = u0*hi[0].z + u1*hi[1].z + u2*hi[2].z + u3*hi[3].z + u4*hi[4].z;
    rh.w = u0*hi[0].w + u1*hi[1].w + u2*hi[2].w + u3*hi[3].w + u4*hi[4].w;
    *(uint4*)(kout + j) = pack8(rl, rh);
  }
}

// ---------------- MFMA GEMM: C_bf16[M,256] = A_bf16 @ Wt^T ------------------------
// SCALE: acc *= ssum[row*4 + col/64] (v-GEMM). SEEPI: fused SE avg/max (o-GEMM).
// BM=128, BN=256, BK=64, 512 threads = 8 waves (2 x 4), 16x16x32 bf16 MFMA.
// NOTE: C may equal A (in-place); C not restrict.
template<int SCALE, int SEEPI>
__global__ __launch_bounds__(512, 4) void gemm_mfma(
    const ushort_t* __restrict__ A, const ushort_t* __restrict__ Wt,
    ushort_t* C, const float* __restrict__ ssum,
    float* __restrict__ ravg, float* __restrict__ rmax) {
  __shared__ __align__(16) ushort_t As_[128 * 64];
  __shared__ __align__(16) ushort_t Bs_[256 * 64];
  __shared__ float redS[8], redM[8];
  const int tid = threadIdx.x;
  const int lane = tid & 63;
  const int w = tid >> 6, wr = w >> 2, wc = w & 3;
  const int row0 = blockIdx.x * 128;
  const int cl = lane & 15, ql = lane >> 4, l7 = lane & 7;

  f32x4 acc[4][4];
#pragma unroll
  for (int i = 0; i < 4; ++i)
#pragma unroll
    for (int j = 0; j < 4; ++j) acc[i][j] = (f32x4){0.f, 0.f, 0.f, 0.f};

  for (int t = 0; t < 4; ++t) {
    const int k0 = t * 64;
    if (t) __syncthreads();
#pragma unroll
    for (int l = 0; l < 2; ++l) {              // A: 1024 16B chunks
      int i = l * 512 + tid;
      int r = i >> 3, c = i & 7;
      uint4 v = *(const uint4*)(A + (size_t)(row0 + r) * 256 + k0 + c * 8);
      *(uint4*)&As_[r * 64 + ((c ^ (r & 7)) * 8)] = v;
    }
#pragma unroll
    for (int l = 0; l < 4; ++l) {              // B: 2048 16B chunks
      int i = l * 512 + tid;
      int n = i >> 3, c = i & 7;
      uint4 v = *(const uint4*)(Wt + (size_t)n * 256 + k0 + c * 8);
      *(uint4*)&Bs_[n * 64 + ((c ^ (n & 7)) * 8)] = v;
    }
    __syncthreads();
#pragma unroll
    for (int kk = 0; kk < 2; ++kk) {
      const int offk = (((kk << 2) | ql) ^ l7) * 8;
      bf16x8 bfr[4], afr[4];
#pragma unroll
      for (int ni = 0; ni < 4; ++ni)
        bfr[ni] = *(const bf16x8*)&Bs_[(wc * 64 + ni * 16 + cl) * 64 + offk];
#pragma unroll
      for (int mi = 0; mi < 4; ++mi)
        afr[mi] = *(const bf16x8*)&As_[(wr * 64 + mi * 16 + cl) * 64 + offk];
#pragma unroll
      for (int mi = 0; mi < 4; ++mi)
#pragma unroll
        for (int ni = 0; ni < 4; ++ni)
          acc[mi][ni] = __builtin_amdgcn_mfma_f32_16x16x32_bf16(afr[mi], bfr[ni], acc[mi][ni], 0, 0, 0);
    }
  }
  // epilogue: D row = wr*64+mi*16+ql*4+r, col = wc*64+ni*16+cl
  float lsum = 0.f, lmax = -3.4e38f;
#pragma unroll
  for (int mi = 0; mi < 4; ++mi) {
    float sc[4];
    if (SCALE) {
#pragma unroll
      for (int r = 0; r < 4; ++r)
        sc[r] = ssum[(size_t)(row0 + wr * 64 + mi * 16 + ql * 4 + r) * 4 + wc];
    }
#pragma unroll
    for (int ni = 0; ni < 4; ++ni) {
      int col = wc * 64 + ni * 16 + cl;
      f32x4 v = acc[mi][ni];
#pragma unroll
      for (int r = 0; r < 4; ++r) {
        int row = row0 + wr * 64 + mi * 16 + ql * 4 + r;
        float f = v[r];
        if (SCALE) f *= sc[r];
        C[(size_t)row * 256 + col] = f2bf(f);
        if (SEEPI) { lsum += f; lmax = fmaxf(lmax, f); }
      }
    }
  }
  if (SEEPI) {
#pragma unroll
    for (int off = 32; off; off >>= 1) {
      lsum += __shfl_xor(lsum, off);
      lmax = fmaxf(lmax, __shfl_xor(lmax, off));
    }
    if (lane == 0) { redS[w] = lsum; redM[w] = lmax; }
    __syncthreads();
    if (tid < 2) {                             // group bt = row0/64 + tid
      float s = redS[tid * 4] + redS[tid * 4 + 1] + redS[tid * 4 + 2] + redS[tid * 4 + 3];
      float m = fmaxf(fmaxf(redM[tid * 4], redM[tid * 4 + 1]),
                      fmaxf(redM[tid * 4 + 2], redM[tid * 4 + 3]));
      ravg[blockIdx.x * 2 + tid] = s * (1.f / 16384.f);
      rmax[blockIdx.x * 2 + tid] = m;
    }
  }
}

// ---------------- score via MFMA ---------------------------------------------------
// ssum[n,t,c] = sum_s sigmoid(qk/8)*prior[t,s,c] - bps[n%256,t,c]
// Block = one n, 4 waves; wave w owns col-strip c in [w*16, w*16+16).
__global__ __launch_bounds__(256) void score_mfma(const ushort_t* __restrict__ q,
                                                  const ushort_t* __restrict__ kbuf,
                                                  const float* __restrict__ prior,
                                                  const float* __restrict__ bps,
                                                  float* __restrict__ ssum) {
  const int n = blockIdx.x;
  const int tid = threadIdx.x;
  const int lane = tid & 63;
  const int w = tid >> 6;
  const int cl = lane & 15, ql = lane >> 4;
  const int nb = n & 255;
  const int c = w * 16 + cl;
  const ushort_t* kb = kbuf + (size_t)(n >> 2) * 16384 + (n & 3) * 64;
  bf16x8 kfr0 = *(const bf16x8*)(kb + c * 256 + ql * 8);
  bf16x8 kfr1 = *(const bf16x8*)(kb + c * 256 + ql * 8 + 32);
  for (int t = 0; t < 5; ++t) {
    const ushort_t* qt = q + (size_t)n * 20480 + t * 4096;
    f32x4 acc[4];
#pragma unroll
    for (int si = 0; si < 4; ++si) {
      bf16x8 a0 = *(const bf16x8*)(qt + (si * 16 + cl) * 64 + ql * 8);
      bf16x8 a1 = *(const bf16x8*)(qt + (si * 16 + cl) * 64 + ql * 8 + 32);
      f32x4 z = (f32x4){0.f, 0.f, 0.f, 0.f};
      z = __builtin_amdgcn_mfma_f32_16x16x32_bf16(a0, kfr0, z, 0, 0, 0);
      z = __builtin_amdgcn_mfma_f32_16x16x32_bf16(a1, kfr1, z, 0, 0, 0);
      acc[si] = z;
    }
    const float* pp = prior + t * 4096;
    float colsum = 0.f;
#pragma unroll
    for (int si = 0; si < 4; ++si) {
#pragma unroll
      for (int r = 0; r < 4; ++r) {
        int s = si * 16 + ql * 4 + r;
        float sg = 1.f / (1.f + __expf(-acc[si][r] * 0.125f));
        colsum += sg * pp[s * 64 + c];
      }
    }
    colsum += __shfl_xor(colsum, 16);
    colsum += __shfl_xor(colsum, 32);
    if (ql == 0)
      ssum[(size_t)n * 320 + t * 64 + c] = colsum - bps[((size_t)nb * 5 + t) * 64 + c];
  }
}

// ---------------- final: out = bf16(o)*se[b,t] + bf16(x), se computed inline ------
// Each block covers 1024 consecutive floats => exactly one (b,t) group.
__global__ __launch_bounds__(256) void final_kernel(
    const ushort_t* __restrict__ xb, const ushort_t* __restrict__ ob,
    const float* __restrict__ ravg, const float* __restrict__ rmax,
    const float* __restrict__ fc1w, const float* __restrict__ fc1b,
    const float* __restrict__ fc2w, const float* __restrict__ fc2b,
    const float* __restrict__ bili, float* __restrict__ out) {
  __shared__ float sse;
  int i = blockIdx.x * 256 + threadIdx.x;      // float4 id, 5242880
  size_t j = (size_t)i * 4;
  int bt = (int)(j >> 14);
  uint2 uo = *(const uint2*)(ob + j);          // issue loads before serial SE
  uint2 ux = *(const uint2*)(xb + j);
  if (threadIdx.x == 0) {
    int b = bt / 5, t = bt % 5;
    float avg[5], mx[5];
    for (int tt = 0; tt < 5; ++tt) { avg[tt] = ravg[b * 5 + tt]; mx[tt] = rmax[b * 5 + tt]; }
    float w = bili[0];
    float s12[2];
    for (int p = 0; p < 2; ++p) {
      const float* in = p == 0 ? avg : mx;
      float a = fc2b[t];
      for (int jj = 0; jj < 25; ++jj) {
        float hh = fc1b[jj];
        for (int tt = 0; tt < 5; ++tt) hh += in[tt] * fc1w[tt * 25 + jj];
        a += fmaxf(hh, 0.f) * fc2w[jj * 5 + t];
      }
      s12[p] = 1.f / (1.f + __expf(-a));
    }
    sse = (1.f - w) * s12[0] + w * s12[1];
  }
  __syncthreads();
  float s = sse;
  float4 r = {bflo(uo.x) * s + bflo(ux.x), bfhi(uo.x) * s + bfhi(ux.x),
              bflo(uo.y) * s + bflo(ux.y), bfhi(uo.y) * s + bfhi(ux.y)};
  *(float4*)(out + j) = r;
}

extern "C" void kernel_launch(void* const* d_in, const int* in_sizes, int n_in,
                              void* d_out, int out_size, void* d_ws, size_t ws_size,
                              hipStream_t stream) {
  const float* x     = (const float*)d_in[0];
  const float* bias  = (const float*)d_in[1];
  const float* Wq    = (const float*)d_in[2];
  const float* Wv    = (const float*)d_in[3];
  const float* Wo    = (const float*)d_in[4];
  const float* u_t   = (const float*)d_in[5];
  const float* dis   = (const float*)d_in[6];
  const float* sigma = (const float*)d_in[7];
  const float* fc1w  = (const float*)d_in[8];
  const float* fc1b  = (const float*)d_in[9];
  const float* fc2w  = (const float*)d_in[10];
  const float* fc2b  = (const float*)d_in[11];
  const float* bili  = (const float*)d_in[12];
  float* out = (float*)d_out;

  // workspace layout (bytes), ~94.5 MB. qvb carries q -> v*ssum -> o (in place).
  char* wsb = (char*)d_ws;
  ushort_t* xbuf = (ushort_t*)wsb;             wsb += 41943040;  // bf16(x), alive to end
  ushort_t* qvb  = (ushort_t*)wsb;             wsb += 41943040;  // q / v*s / o
  ushort_t* kb   = (ushort_t*)wsb;             wsb += 8388608;   // k bf16 [B,S,F]
  ushort_t* Wt   = (ushort_t*)wsb;             wsb += 393216;    // 3 x W^T bf16
  float*    ssum = (float*)wsb;                wsb += 1310720;
  float*    prior= (float*)wsb;                wsb += 81920;
  float*    bps  = (float*)wsb;                wsb += 327680;
  float*    ravg = (float*)wsb;                wsb += 5120;
  float*    rmax = (float*)wsb;                wsb += 5120;

  // 1) fused prep: Wt | prior | bps | (k, xb)
  prep_kernel<<<4176, 256, 0, stream>>>(x, u_t, Wq, Wv, Wo, dis, sigma, bias,
                                        Wt, prior, bps, kb, xbuf);
  // 2) q = xb @ Wq
  gemm_mfma<0, 0><<<640, 512, 0, stream>>>(xbuf, Wt, qvb, nullptr, nullptr, nullptr);
  // 3) score
  score_mfma<<<1024, 256, 0, stream>>>(qvb, kb, prior, bps, ssum);
  // 4) v = xb @ Wv, scaled by ssum in epilogue (overwrites q)
  gemm_mfma<1, 0><<<640, 512, 0, stream>>>(xbuf, Wt + 65536, qvb, ssum, nullptr, nullptr);
  // 5) o = (v.*s) @ Wo -> qvb IN PLACE, fused SE avg/max
  gemm_mfma<0, 1><<<640, 512, 0, stream>>>(qvb, Wt + 131072, qvb, nullptr, ravg, rmax);
  // 6) final with inline SE MLP
  final_kernel<<<20480, 256, 0, stream>>>(xbuf, qvb, ravg, rmax,
                                          fc1w, fc1b, fc2w, fc2b, bili, out);
}